// Round 4
// baseline (168.464 us; speedup 1.0000x reference)
//
#include <hip/hip_runtime.h>
#include <math.h>

// ---------------------------------------------------------------------------
// AsymQuantMatMul: A[4096,2048] fp32, B[2048,4096] fp32 -> out[4096,4096] fp32
// R8: GEMM rebuilt on the counted-vmcnt double-buffer schedule (T3+T4+T5):
//     256x256 block, BK=128, 512 thr (8 waves 2Mx4N, per-wave 128x64),
//     LDS 2x64KB = 128 KiB -> 1 block/CU. Raw s_barrier + s_waitcnt vmcnt(8)
//     (never 0 in main loop) so global_load_lds prefetches survive barriers.
//     Verified 0-conflict 3-bit XOR swizzle + fragment geometry unchanged.
//     Stage kernels unchanged. (R4 44.5us / R6 dbuf-drain0 49.6 / R7 46.7 all
//     pinned at ~37% of i8 ceiling = the 2-barrier drain-0 structural limit.)
// ---------------------------------------------------------------------------

#define M_DIM 4096
#define K_DIM 2048
#define N_DIM 4096

using int4v = __attribute__((ext_vector_type(4))) int;

typedef __attribute__((address_space(1))) const void glb_cv;
typedef __attribute__((address_space(3))) void lds_v;

__device__ __forceinline__ int qbyte(float x, float rs, float z) {
    // reference: clip(round(x/scale) + zero, 0, 255), shifted by -128
    float q = fminf(fmaxf(rintf(x * rs) + z, 0.0f), 255.0f);
    return (int)q - 128;
}

__device__ __forceinline__ int sum4(int w) {
    return (int)(signed char)(w) + (int)(signed char)(w >> 8) +
           (int)(signed char)(w >> 16) + (int)(signed char)(w >> 24);
}

__device__ __forceinline__ void blocksync() {
    asm volatile("" ::: "memory");   // compiler fence: no LDS motion across
    __builtin_amdgcn_s_barrier();
    asm volatile("" ::: "memory");
}

// ---- Kernel 1: per-block min/max partials (512 A + 512 B); zero colB ----
__global__ void minmax_stage1(const float* __restrict__ A,
                              const float* __restrict__ B,
                              float* __restrict__ partials,
                              int* __restrict__ colB) {
    int b = blockIdx.x;
    if (b < 16) colB[b * 256 + threadIdx.x] = 0;  // init for quant atomics
    const float* src = (b < 512) ? A : B;
    int lb = (b < 512) ? b : b - 512;
    const float4* v = (const float4*)src + (long)lb * 4096;  // 4096 float4/block
    float mn = INFINITY, mx = -INFINITY;
    for (int i = threadIdx.x; i < 4096; i += 256) {
        float4 x = v[i];
        mn = fminf(mn, fminf(fminf(x.x, x.y), fminf(x.z, x.w)));
        mx = fmaxf(mx, fmaxf(fmaxf(x.x, x.y), fmaxf(x.z, x.w)));
    }
    for (int off = 32; off; off >>= 1) {
        mn = fminf(mn, __shfl_down(mn, off));
        mx = fmaxf(mx, __shfl_down(mx, off));
    }
    __shared__ float smn[4], smx[4];
    int w = threadIdx.x >> 6;
    if ((threadIdx.x & 63) == 0) { smn[w] = mn; smx[w] = mx; }
    __syncthreads();
    if (threadIdx.x == 0) {
        mn = fminf(fminf(smn[0], smn[1]), fminf(smn[2], smn[3]));
        mx = fmaxf(fmaxf(smx[0], smx[1]), fmaxf(smx[2], smx[3]));
        partials[2 * b] = mn;
        partials[2 * b + 1] = mx;
    }
}

// ---- Kernel 2: fused quantize. Blocks 0..2047: A (2 rows each, row-major
// i8, + row sums). Blocks 2048..4095: B 64x64 tile transpose (+ col sums).
// Every block deterministically re-reduces all partials -> identical qp.
__global__ void quant_fused(const float* __restrict__ A,
                            const float* __restrict__ B,
                            const float* __restrict__ partials,
                            signed char* __restrict__ A8,
                            signed char* __restrict__ B8T,
                            int* __restrict__ rowA,
                            int* __restrict__ colB,
                            float* __restrict__ qp) {
    int b = blockIdx.x, t = threadIdx.x;

    // -- reduce all 1024 partial pairs (L2/L3-cached after kernel 1) --
    float mnA = INFINITY, mxA = -INFINITY, mnB = INFINITY, mxB = -INFINITY;
    for (int i = t; i < 512; i += 256) {
        mnA = fminf(mnA, partials[2 * i]);
        mxA = fmaxf(mxA, partials[2 * i + 1]);
        mnB = fminf(mnB, partials[2 * (i + 512)]);
        mxB = fmaxf(mxB, partials[2 * (i + 512) + 1]);
    }
    for (int off = 32; off; off >>= 1) {
        mnA = fminf(mnA, __shfl_down(mnA, off));
        mxA = fmaxf(mxA, __shfl_down(mxA, off));
        mnB = fminf(mnB, __shfl_down(mnB, off));
        mxB = fmaxf(mxB, __shfl_down(mxB, off));
    }
    __shared__ float sred[4][4];
    int w = t >> 6;
    if ((t & 63) == 0) { sred[w][0] = mnA; sred[w][1] = mxA; sred[w][2] = mnB; sred[w][3] = mxB; }
    __syncthreads();
    mnA = fminf(fminf(sred[0][0], sred[1][0]), fminf(sred[2][0], sred[3][0]));
    mxA = fmaxf(fmaxf(sred[0][1], sred[1][1]), fmaxf(sred[2][1], sred[3][1]));
    mnB = fminf(fminf(sred[0][2], sred[1][2]), fminf(sred[2][2], sred[3][2]));
    mxB = fmaxf(fmaxf(sred[0][3], sred[1][3]), fmaxf(sred[2][3], sred[3][3]));
    float sA = (mxA - mnA) / 255.0f;
    float zA = rintf(-mnA / sA);
    float sB = (mxB - mnB) / 255.0f;
    float zB = rintf(-mnB / sB);
    if (b == 0 && t == 0) { qp[0] = sA; qp[1] = zA; qp[2] = sB; qp[3] = zB; }
    __syncthreads();

    if (b < 2048) {
        // ---- A path: 2 rows of 2048, fused row sums ----
        float rs = 1.0f / sA, z = zA;
        long base = (long)b * 4096 + (long)t * 16;
        const float4* v = (const float4*)(A + base);
        union { signed char c[16]; int4 i4; } u;
        int ls = 0;
#pragma unroll
        for (int j = 0; j < 4; j++) {
            float4 x = v[j];
            int q0 = qbyte(x.x, rs, z), q1 = qbyte(x.y, rs, z);
            int q2 = qbyte(x.z, rs, z), q3 = qbyte(x.w, rs, z);
            u.c[j * 4 + 0] = (signed char)q0;
            u.c[j * 4 + 1] = (signed char)q1;
            u.c[j * 4 + 2] = (signed char)q2;
            u.c[j * 4 + 3] = (signed char)q3;
            ls += q0 + q1 + q2 + q3;
        }
        *(int4*)(A8 + base) = u.i4;
        for (int off = 32; off; off >>= 1) ls += __shfl_down(ls, off);
        __shared__ int wsum[4];
        if ((t & 63) == 0) wsum[t >> 6] = ls;
        __syncthreads();
        if (t == 0) rowA[b * 2] = wsum[0] + wsum[1];
        if (t == 128) rowA[b * 2 + 1] = wsum[2] + wsum[3];
    } else {
        // ---- B path: 64x64 tile transpose via int-packed LDS, col sums ----
        float rs = 1.0f / sB, z = zB;
        int bb = b - 2048;
        int k0 = (bb & 31) * 64, n0 = (bb >> 5) * 64;
        __shared__ int tile[64][17];  // [n][k/4], +1 pad
        int cn = (t & 15) * 4;  // n offset within tile
        int kg = (t >> 4) * 4;  // k offset within tile
        int w0 = 0, w1 = 0, w2 = 0, w3 = 0;
#pragma unroll
        for (int r = 0; r < 4; r++) {
            float4 x = *(const float4*)&B[(long)(k0 + kg + r) * N_DIM + n0 + cn];
            w0 |= (qbyte(x.x, rs, z) & 255) << (8 * r);
            w1 |= (qbyte(x.y, rs, z) & 255) << (8 * r);
            w2 |= (qbyte(x.z, rs, z) & 255) << (8 * r);
            w3 |= (qbyte(x.w, rs, z) & 255) << (8 * r);
        }
        int kc = kg >> 2;
        tile[cn + 0][kc] = w0;
        tile[cn + 1][kc] = w1;
        tile[cn + 2][kc] = w2;
        tile[cn + 3][kc] = w3;
        __syncthreads();
        int n2 = t >> 2, kb = (t & 3) * 4;
        int4 v;
        v.x = tile[n2][kb + 0];
        v.y = tile[n2][kb + 1];
        v.z = tile[n2][kb + 2];
        v.w = tile[n2][kb + 3];
        *(int4*)&B8T[(long)(n0 + n2) * K_DIM + k0 + (t & 3) * 16] = v;
        int ls = sum4(v.x) + sum4(v.y) + sum4(v.z) + sum4(v.w);
        ls += __shfl_down(ls, 2);
        ls += __shfl_down(ls, 1);
        if ((t & 3) == 0) atomicAdd(&colB[n0 + n2], ls);
    }
}

// ---- Kernel 3: i8 MFMA GEMM, 256x256 block, counted-vmcnt dbuf pipeline ----
// 8 waves (2Mx4N), per-wave 128x64 = 8x4 frags of 16x16x64. BK=128 -> 16
// K-tiles, 2 k-slices each. LDS 2x(A 32KB + B 32KB) = 128 KiB, 1 block/CU.
// Schedule per K-tile: compute both slices on buf[cb] -> s_barrier (reads
// done) -> issue tile it+2's 8 global_load_lds into buf[cb] -> s_waitcnt
// vmcnt(8) (tile it+1 landed; it+2 stays in flight) -> s_barrier (publish).
// No vmcnt(0) until the tail. LDS: 16B chunk c of row r at slot c^(r&7)
// (verified 0-conflict geometry; row&7 == mrow&7 since wm,wn = 0 mod 64).
__global__ __launch_bounds__(512, 2) void gemm_i8(
        const signed char* __restrict__ A8,
        const signed char* __restrict__ B8T,
        const int* __restrict__ rowA,
        const int* __restrict__ colB,
        const float* __restrict__ qp,
        float* __restrict__ out) {
    __shared__ __align__(16) signed char As[2][256 * 128];  // 64 KB
    __shared__ __align__(16) signed char Bs[2][256 * 128];  // 64 KB

    // XCD-keyed block swizzle: 16x16 tile grid, 256 blocks (256%8==0,
    // bijective). Each XCD owns a 4mt x 8nt region.
    int b = blockIdx.x;
    int xcd = b & 7, i0 = b >> 3;          // i0: 0..31
    int mt = (xcd >> 1) * 4 + (i0 >> 3);   // 0..15
    int nt = (xcd & 1) * 8 + (i0 & 7);     // 0..15
    int r0 = mt * 256, c0 = nt * 256;

    int t = threadIdx.x, lane = t & 63, wave = t >> 6;
    int mrow = lane & 15;
    int g = lane >> 4;               // k-group 0..3
    int wm = (wave >> 2) * 128;      // wave m offset: 0,128
    int wn = (wave & 3) * 64;        // wave n offset: 0,64,128,192

    int4v acc[8][4];
#pragma unroll
    for (int i = 0; i < 8; i++)
#pragma unroll
        for (int jj = 0; jj < 4; jj++) acc[i][jj] = (int4v){0, 0, 0, 0};

    // Staging offsets: LDS chunk ch -> row=ch>>3, slot p=ch&7 holds global
    // chunk p ^ (row&7). A and B each: 2048 chunks, 4 per thread.
    long aoff[4], boff[4];
#pragma unroll
    for (int j = 0; j < 4; j++) {
        int ch = t + 512 * j;        // 0..2047
        int row = ch >> 3, p = ch & 7;
        int gk = p ^ (row & 7);
        aoff[j] = (long)(r0 + row) * K_DIM + gk * 16;
        boff[j] = (long)(c0 + row) * K_DIM + gk * 16;
    }

    int swz = (mrow & 7);            // read-side XOR
    int aBase = (wm + mrow) * 128;   // i stride 16*128 = 2048
    int bBase = (wn + mrow) * 128;   // jj stride 2048

#define STAGE(kbyte, buf) do {                                                  \
    _Pragma("unroll")                                                           \
    for (int j_ = 0; j_ < 4; j_++)                                              \
        __builtin_amdgcn_global_load_lds((glb_cv*)(A8 + aoff[j_] + (kbyte)),    \
            (lds_v*)(As[buf] + (t + 512 * j_) * 16), 16, 0, 0);                 \
    _Pragma("unroll")                                                           \
    for (int j_ = 0; j_ < 4; j_++)                                              \
        __builtin_amdgcn_global_load_lds((glb_cv*)(B8T + boff[j_] + (kbyte)),   \
            (lds_v*)(Bs[buf] + (t + 512 * j_) * 16), 16, 0, 0);                 \
} while (0)

#define SLICE(cb, ks) do {                                                      \
    const int koff_ = ((((ks) * 4 + g) ^ swz) << 4);                            \
    int4v af[8], bf[4];                                                         \
    _Pragma("unroll")                                                           \
    for (int i_ = 0; i_ < 8; i_++)                                              \
        af[i_] = *(const int4v*)&As[cb][aBase + i_ * 2048 + koff_];             \
    _Pragma("unroll")                                                           \
    for (int j_ = 0; j_ < 4; j_++)                                              \
        bf[j_] = *(const int4v*)&Bs[cb][bBase + j_ * 2048 + koff_];             \
    __builtin_amdgcn_s_setprio(1);                                              \
    _Pragma("unroll")                                                           \
    for (int i_ = 0; i_ < 8; i_++)                                              \
        _Pragma("unroll")                                                       \
        for (int j_ = 0; j_ < 4; j_++)                                          \
            acc[i_][j_] = __builtin_amdgcn_mfma_i32_16x16x64_i8(                \
                af[i_], bf[j_], acc[i_][j_], 0, 0, 0);                          \
    __builtin_amdgcn_s_setprio(0);                                              \
} while (0)

    // Prologue: tiles 0,1 in flight; force only tile 0, leave tile 1 flying.
    STAGE(0, 0);
    STAGE(128, 1);
    asm volatile("s_waitcnt vmcnt(8)" ::: "memory");
    blocksync();

    for (int it = 0; it < 16; ++it) {
        int cb = it & 1;
        SLICE(cb, 0);
        SLICE(cb, 1);
        blocksync();                       // all waves done reading buf[cb]
        if (it < 14) STAGE((it + 2) * 128, cb);
        if (it < 15) {
            if (it < 14)
                asm volatile("s_waitcnt vmcnt(8)" ::: "memory");  // tile it+1 in
            else
                asm volatile("s_waitcnt vmcnt(0)" ::: "memory");  // tail drain
            blocksync();                   // publish tile it+1
        }
    }

#undef STAGE
#undef SLICE

    // Epilogue: out = sA*sB*(acc + cB*rowA[m] + cA*colB[n] + K*cA*cB)
    float sA = qp[0], zA = qp[1], sB = qp[2], zB = qp[3];
    int cA = 128 - (int)zA, cB = 128 - (int)zB;
    float ss = sA * sB;
    int Kzz = K_DIM * cA * cB;
    int ocol = c0 + wn + mrow;
    int orow = r0 + wm + g * 4;
    int can[4];
#pragma unroll
    for (int jj = 0; jj < 4; jj++) can[jj] = cA * colB[ocol + jj * 16];
#pragma unroll
    for (int i = 0; i < 8; i++) {
#pragma unroll
        for (int rr = 0; rr < 4; rr++) {
            int row = orow + i * 16 + rr;
            int ra = cB * rowA[row] + Kzz;
            long rbase = (long)row * N_DIM;
#pragma unroll
            for (int jj = 0; jj < 4; jj++) {
                int v = acc[i][jj][rr] + ra + can[jj];
                __builtin_nontemporal_store(ss * (float)v, &out[rbase + ocol + jj * 16]);
            }
        }
    }
}

extern "C" void kernel_launch(void* const* d_in, const int* in_sizes, int n_in,
                              void* d_out, int out_size, void* d_ws, size_t ws_size,
                              hipStream_t stream) {
    const float* A = (const float*)d_in[0];
    const float* B = (const float*)d_in[1];
    float* out = (float*)d_out;
    char* ws = (char*)d_ws;

    signed char* A8  = (signed char*)ws;                    //  8 MB
    signed char* B8T = (signed char*)(ws + 8388608);        //  8 MB
    int*   rowA      = (int*)(ws + 16777216);               // 16 KB
    int*   colB      = (int*)(ws + 16793600);               // 16 KB
    float* partials  = (float*)(ws + 16809984);             //  8 KB
    float* qp        = (float*)(ws + 16818176);             // 16 B

    minmax_stage1<<<1024, 256, 0, stream>>>(A, B, partials, colB);
    quant_fused<<<4096, 256, 0, stream>>>(A, B, partials, A8, B8T, rowA, colB, qp);
    gemm_i8<<<256, 512, 0, stream>>>(A8, B8T, rowA, colB, qp, out);
}

// Round 5
// 168.093 us; speedup vs baseline: 1.0022x; 1.0022x over previous
//
#include <hip/hip_runtime.h>
#include <math.h>

// ---------------------------------------------------------------------------
// AsymQuantMatMul: A[4096,2048] fp32, B[2048,4096] fp32 -> out[4096,4096] fp32
// R9: GEMM = 256x128 block, 4 fat waves (2Mx2N, per-wave 128x64, acc 128
//     regs -> 2 waves/SIMD), BK=64, dbuf LDS 48KB -> 2 blocks/CU (the
//     occupancy class that has never lost). Fine-grained pipeline per tile:
//     12 ds_read -> lgkmcnt(0)+barrier (buf free) -> STAGE(kt+2) issued
//     BEFORE the 32-MFMA cluster (1.5 tiles of lead) -> vmcnt(6) counted
//     (never 0 in main loop) -> barrier. 64B-row swizzle slot=c^((row>>1)&3)
//     (same 0-conflict class as verified R2; content map: lane(g,mrow) reads
//     global k-chunk g, identical operand semantics). Epilogue verbatim R8.
// ---------------------------------------------------------------------------

#define M_DIM 4096
#define K_DIM 2048
#define N_DIM 4096

using int4v = __attribute__((ext_vector_type(4))) int;

typedef __attribute__((address_space(1))) const void glb_cv;
typedef __attribute__((address_space(3))) void lds_v;

__device__ __forceinline__ int qbyte(float x, float rs, float z) {
    // reference: clip(round(x/scale) + zero, 0, 255), shifted by -128
    float q = fminf(fmaxf(rintf(x * rs) + z, 0.0f), 255.0f);
    return (int)q - 128;
}

__device__ __forceinline__ int sum4(int w) {
    return (int)(signed char)(w) + (int)(signed char)(w >> 8) +
           (int)(signed char)(w >> 16) + (int)(signed char)(w >> 24);
}

__device__ __forceinline__ void blocksync() {
    asm volatile("" ::: "memory");
    __builtin_amdgcn_s_barrier();
    asm volatile("" ::: "memory");
}

// ---- Kernel 1: per-block min/max partials (512 A + 512 B); zero colB ----
__global__ void minmax_stage1(const float* __restrict__ A,
                              const float* __restrict__ B,
                              float* __restrict__ partials,
                              int* __restrict__ colB) {
    int b = blockIdx.x;
    if (b < 16) colB[b * 256 + threadIdx.x] = 0;  // init for quant atomics
    const float* src = (b < 512) ? A : B;
    int lb = (b < 512) ? b : b - 512;
    const float4* v = (const float4*)src + (long)lb * 4096;  // 4096 float4/block
    float mn = INFINITY, mx = -INFINITY;
    for (int i = threadIdx.x; i < 4096; i += 256) {
        float4 x = v[i];
        mn = fminf(mn, fminf(fminf(x.x, x.y), fminf(x.z, x.w)));
        mx = fmaxf(mx, fmaxf(fmaxf(x.x, x.y), fmaxf(x.z, x.w)));
    }
    for (int off = 32; off; off >>= 1) {
        mn = fminf(mn, __shfl_down(mn, off));
        mx = fmaxf(mx, __shfl_down(mx, off));
    }
    __shared__ float smn[4], smx[4];
    int w = threadIdx.x >> 6;
    if ((threadIdx.x & 63) == 0) { smn[w] = mn; smx[w] = mx; }
    __syncthreads();
    if (threadIdx.x == 0) {
        mn = fminf(fminf(smn[0], smn[1]), fminf(smn[2], smn[3]));
        mx = fmaxf(fmaxf(smx[0], smx[1]), fmaxf(smx[2], smx[3]));
        partials[2 * b] = mn;
        partials[2 * b + 1] = mx;
    }
}

// ---- Kernel 2: fused quantize. Blocks 0..2047: A (2 rows each, row-major
// i8, + row sums). Blocks 2048..4095: B 64x64 tile transpose (+ col sums).
// Every block deterministically re-reduces all partials -> identical qp.
__global__ void quant_fused(const float* __restrict__ A,
                            const float* __restrict__ B,
                            const float* __restrict__ partials,
                            signed char* __restrict__ A8,
                            signed char* __restrict__ B8T,
                            int* __restrict__ rowA,
                            int* __restrict__ colB,
                            float* __restrict__ qp) {
    int b = blockIdx.x, t = threadIdx.x;

    // -- reduce all 1024 partial pairs (L2/L3-cached after kernel 1) --
    float mnA = INFINITY, mxA = -INFINITY, mnB = INFINITY, mxB = -INFINITY;
    for (int i = t; i < 512; i += 256) {
        mnA = fminf(mnA, partials[2 * i]);
        mxA = fmaxf(mxA, partials[2 * i + 1]);
        mnB = fminf(mnB, partials[2 * (i + 512)]);
        mxB = fmaxf(mxB, partials[2 * (i + 512) + 1]);
    }
    for (int off = 32; off; off >>= 1) {
        mnA = fminf(mnA, __shfl_down(mnA, off));
        mxA = fmaxf(mxA, __shfl_down(mxA, off));
        mnB = fminf(mnB, __shfl_down(mnB, off));
        mxB = fmaxf(mxB, __shfl_down(mxB, off));
    }
    __shared__ float sred[4][4];
    int w = t >> 6;
    if ((t & 63) == 0) { sred[w][0] = mnA; sred[w][1] = mxA; sred[w][2] = mnB; sred[w][3] = mxB; }
    __syncthreads();
    mnA = fminf(fminf(sred[0][0], sred[1][0]), fminf(sred[2][0], sred[3][0]));
    mxA = fmaxf(fmaxf(sred[0][1], sred[1][1]), fmaxf(sred[2][1], sred[3][1]));
    mnB = fminf(fminf(sred[0][2], sred[1][2]), fminf(sred[2][2], sred[3][2]));
    mxB = fmaxf(fmaxf(sred[0][3], sred[1][3]), fmaxf(sred[2][3], sred[3][3]));
    float sA = (mxA - mnA) / 255.0f;
    float zA = rintf(-mnA / sA);
    float sB = (mxB - mnB) / 255.0f;
    float zB = rintf(-mnB / sB);
    if (b == 0 && t == 0) { qp[0] = sA; qp[1] = zA; qp[2] = sB; qp[3] = zB; }
    __syncthreads();

    if (b < 2048) {
        // ---- A path: 2 rows of 2048, fused row sums ----
        float rs = 1.0f / sA, z = zA;
        long base = (long)b * 4096 + (long)t * 16;
        const float4* v = (const float4*)(A + base);
        union { signed char c[16]; int4 i4; } u;
        int ls = 0;
#pragma unroll
        for (int j = 0; j < 4; j++) {
            float4 x = v[j];
            int q0 = qbyte(x.x, rs, z), q1 = qbyte(x.y, rs, z);
            int q2 = qbyte(x.z, rs, z), q3 = qbyte(x.w, rs, z);
            u.c[j * 4 + 0] = (signed char)q0;
            u.c[j * 4 + 1] = (signed char)q1;
            u.c[j * 4 + 2] = (signed char)q2;
            u.c[j * 4 + 3] = (signed char)q3;
            ls += q0 + q1 + q2 + q3;
        }
        *(int4*)(A8 + base) = u.i4;
        for (int off = 32; off; off >>= 1) ls += __shfl_down(ls, off);
        __shared__ int wsum[4];
        if ((t & 63) == 0) wsum[t >> 6] = ls;
        __syncthreads();
        if (t == 0) rowA[b * 2] = wsum[0] + wsum[1];
        if (t == 128) rowA[b * 2 + 1] = wsum[2] + wsum[3];
    } else {
        // ---- B path: 64x64 tile transpose via int-packed LDS, col sums ----
        float rs = 1.0f / sB, z = zB;
        int bb = b - 2048;
        int k0 = (bb & 31) * 64, n0 = (bb >> 5) * 64;
        __shared__ int tile[64][17];  // [n][k/4], +1 pad
        int cn = (t & 15) * 4;  // n offset within tile
        int kg = (t >> 4) * 4;  // k offset within tile
        int w0 = 0, w1 = 0, w2 = 0, w3 = 0;
#pragma unroll
        for (int r = 0; r < 4; r++) {
            float4 x = *(const float4*)&B[(long)(k0 + kg + r) * N_DIM + n0 + cn];
            w0 |= (qbyte(x.x, rs, z) & 255) << (8 * r);
            w1 |= (qbyte(x.y, rs, z) & 255) << (8 * r);
            w2 |= (qbyte(x.z, rs, z) & 255) << (8 * r);
            w3 |= (qbyte(x.w, rs, z) & 255) << (8 * r);
        }
        int kc = kg >> 2;
        tile[cn + 0][kc] = w0;
        tile[cn + 1][kc] = w1;
        tile[cn + 2][kc] = w2;
        tile[cn + 3][kc] = w3;
        __syncthreads();
        int n2 = t >> 2, kb = (t & 3) * 4;
        int4 v;
        v.x = tile[n2][kb + 0];
        v.y = tile[n2][kb + 1];
        v.z = tile[n2][kb + 2];
        v.w = tile[n2][kb + 3];
        *(int4*)&B8T[(long)(n0 + n2) * K_DIM + k0 + (t & 3) * 16] = v;
        int ls = sum4(v.x) + sum4(v.y) + sum4(v.z) + sum4(v.w);
        ls += __shfl_down(ls, 2);
        ls += __shfl_down(ls, 1);
        if ((t & 3) == 0) atomicAdd(&colB[n0 + n2], ls);
    }
}

// ---- Kernel 3: i8 MFMA GEMM, 256x128 block, 256 thr, counted-vmcnt dbuf ----
// 4 waves (2Mx2N), per-wave 128x64 = 8x4 frags of 16x16x64. BK=64 -> 32
// K-tiles. LDS 2x(A 16KB + B 8KB) = 48 KB -> 2 blocks/CU (VGPR ~190 ->
// 2 waves/SIMD; 2 blocks x 4 waves = 8 waves/CU).
// Per tile kt (buf cb=kt&1): 12 ds_read -> lgkmcnt(0) -> barrier (buf[cb]
// free block-wide) -> STAGE(kt+2 -> buf[cb]) -> 32 MFMA (loads fly under
// this tile AND tile kt+1) -> s_waitcnt vmcnt(6) (tile kt+1 landed, kt+2
// in flight; 0 only at tail) -> barrier (publish buf[cb^1]).
// 64B rows: LDS slot s of row r holds global chunk s^((r>>1)&3); read at
// slot g^((mrow>>1)&3) -> content = chunk g (operand map identical to the
// verified R2 geometry; 8-consecutive-lane bank tiling exact, 0-conflict).
__global__ __launch_bounds__(256, 2) void gemm_i8(
        const signed char* __restrict__ A8,
        const signed char* __restrict__ B8T,
        const int* __restrict__ rowA,
        const int* __restrict__ colB,
        const float* __restrict__ qp,
        float* __restrict__ out) {
    __shared__ __align__(16) signed char As[2][256 * 64];  // 2 x 16 KB
    __shared__ __align__(16) signed char Bs[2][128 * 64];  // 2 x 8 KB

    // XCD-keyed block swizzle: 16(mt) x 32(nt) tile grid, 512 blocks.
    // Each XCD owns an 8x8 region (A 4MB + B 2MB working set).
    int b = blockIdx.x;
    int xcd = b & 7, i0 = b >> 3;              // i0: 0..63
    int mt = (xcd >> 2) * 8 + (i0 >> 3);       // 0..15
    int nt = (xcd & 3) * 8 + (i0 & 7);         // 0..31
    int r0 = mt * 256, c0 = nt * 128;

    int t = threadIdx.x, lane = t & 63, wave = t >> 6;
    int mrow = lane & 15;
    int g = lane >> 4;               // k-group 0..3
    int wm = (wave >> 1) * 128;      // wave m offset: 0,128
    int wn = (wave & 1) * 64;        // wave n offset: 0,64

    int4v acc[8][4];
#pragma unroll
    for (int i = 0; i < 8; i++)
#pragma unroll
        for (int jj = 0; jj < 4; jj++) acc[i][jj] = (int4v){0, 0, 0, 0};

    // Staging: A tile = 256 rows x 64 B = 1024 chunks (4/thread);
    //          B tile = 128 rows x 64 B =  512 chunks (2/thread).
    // LDS chunk ch -> row=ch>>2, slot p=ch&3 holds global chunk p^((row>>1)&3).
    long aoff[4], boff[2];
#pragma unroll
    for (int j = 0; j < 4; j++) {
        int ch = t + 256 * j;        // 0..1023
        int row = ch >> 2, p = ch & 3;
        int gk = p ^ ((row >> 1) & 3);
        aoff[j] = (long)(r0 + row) * K_DIM + gk * 16;
    }
#pragma unroll
    for (int j = 0; j < 2; j++) {
        int ch = t + 256 * j;        // 0..511
        int row = ch >> 2, p = ch & 3;
        int gk = p ^ ((row >> 1) & 3);
        boff[j] = (long)(c0 + row) * K_DIM + gk * 16;
    }

    int slot = g ^ ((mrow >> 1) & 3);            // read-side swizzle
    int aBase = (wm + mrow) * 64 + slot * 16;    // i stride 16*64 = 1024
    int bBase = (wn + mrow) * 64 + slot * 16;    // jj stride 1024

#define STAGE(BUF, KT) do {                                                     \
    long kb_ = (long)(KT) * 64;                                                 \
    _Pragma("unroll")                                                           \
    for (int j_ = 0; j_ < 4; j_++)                                              \
        __builtin_amdgcn_global_load_lds((glb_cv*)(A8 + aoff[j_] + kb_),        \
            (lds_v*)(As[BUF] + (t + 256 * j_) * 16), 16, 0, 0);                 \
    _Pragma("unroll")                                                           \
    for (int j_ = 0; j_ < 2; j_++)                                              \
        __builtin_amdgcn_global_load_lds((glb_cv*)(B8T + boff[j_] + kb_),       \
            (lds_v*)(Bs[BUF] + (t + 256 * j_) * 16), 16, 0, 0);                 \
} while (0)

// WAITN: 6 = steady (tile KT+1 landed, KT+2 in flight); 0 = tail drain;
// -1 = skip (last tile).
#define TILE(CB, KT, DOSTAGE, WAITN) do {                                       \
    int4v af[8], bf[4];                                                         \
    _Pragma("unroll")                                                           \
    for (int i_ = 0; i_ < 8; i_++)                                              \
        af[i_] = *(const int4v*)&As[CB][aBase + i_ * 1024];                     \
    _Pragma("unroll")                                                           \
    for (int j_ = 0; j_ < 4; j_++)                                              \
        bf[j_] = *(const int4v*)&Bs[CB][bBase + j_ * 1024];                     \
    asm volatile("s_waitcnt lgkmcnt(0)" ::: "memory");                          \
    __builtin_amdgcn_sched_barrier(0);                                          \
    blocksync();                    /* buf[CB] free block-wide */               \
    if (DOSTAGE) STAGE(CB, (KT) + 2);                                           \
    __builtin_amdgcn_s_setprio(1);                                              \
    _Pragma("unroll")                                                           \
    for (int i_ = 0; i_ < 8; i_++)                                              \
        _Pragma("unroll")                                                       \
        for (int j_ = 0; j_ < 4; j_++)                                          \
            acc[i_][j_] = __builtin_amdgcn_mfma_i32_16x16x64_i8(                \
                af[i_], bf[j_], acc[i_][j_], 0, 0, 0);                          \
    __builtin_amdgcn_s_setprio(0);                                              \
    if ((WAITN) == 6) {                                                         \
        asm volatile("s_waitcnt vmcnt(6)" ::: "memory");                        \
        blocksync();                                                            \
    } else if ((WAITN) == 0) {                                                  \
        asm volatile("s_waitcnt vmcnt(0)" ::: "memory");                        \
        blocksync();                                                            \
    }                                                                           \
} while (0)

    // Prologue: tiles 0,1 staged; force tile 0 (vmcnt(6): 6 newest = tile 1
    // may fly), publish.
    STAGE(0, 0);
    STAGE(1, 1);
    asm volatile("s_waitcnt vmcnt(6)" ::: "memory");
    blocksync();

    for (int kp = 0; kp < 15; ++kp) {
        TILE(0, 2 * kp, 1, 6);
        TILE(1, 2 * kp + 1, 1, 6);
    }
    TILE(0, 30, 0, 0);   // drain tile 31's loads
    TILE(1, 31, 0, -1);  // last tile: no wait needed

#undef STAGE
#undef TILE

    // Epilogue: out = sA*sB*(acc + cB*rowA[m] + cA*colB[n] + K*cA*cB)
    float sA = qp[0], zA = qp[1], sB = qp[2], zB = qp[3];
    int cA = 128 - (int)zA, cB = 128 - (int)zB;
    float ss = sA * sB;
    int Kzz = K_DIM * cA * cB;
    int ocol = c0 + wn + mrow;
    int orow = r0 + wm + g * 4;
    int can[4];
#pragma unroll
    for (int jj = 0; jj < 4; jj++) can[jj] = cA * colB[ocol + jj * 16];
#pragma unroll
    for (int i = 0; i < 8; i++) {
#pragma unroll
        for (int rr = 0; rr < 4; rr++) {
            int row = orow + i * 16 + rr;
            int ra = cB * rowA[row] + Kzz;
            long rbase = (long)row * N_DIM;
#pragma unroll
            for (int jj = 0; jj < 4; jj++) {
                int v = acc[i][jj][rr] + ra + can[jj];
                __builtin_nontemporal_store(ss * (float)v, &out[rbase + ocol + jj * 16]);
            }
        }
    }
}

extern "C" void kernel_launch(void* const* d_in, const int* in_sizes, int n_in,
                              void* d_out, int out_size, void* d_ws, size_t ws_size,
                              hipStream_t stream) {
    const float* A = (const float*)d_in[0];
    const float* B = (const float*)d_in[1];
    float* out = (float*)d_out;
    char* ws = (char*)d_ws;

    signed char* A8  = (signed char*)ws;                    //  8 MB
    signed char* B8T = (signed char*)(ws + 8388608);        //  8 MB
    int*   rowA      = (int*)(ws + 16777216);               // 16 KB
    int*   colB      = (int*)(ws + 16793600);               // 16 KB
    float* partials  = (float*)(ws + 16809984);             //  8 KB
    float* qp        = (float*)(ws + 16818176);             // 16 B

    minmax_stage1<<<1024, 256, 0, stream>>>(A, B, partials, colB);
    quant_fused<<<4096, 256, 0, stream>>>(A, B, partials, A8, B8T, rowA, colB, qp);
    gemm_i8<<<512, 256, 0, stream>>>(A8, B8T, rowA, colB, qp, out);
}

// Round 6
// 163.674 us; speedup vs baseline: 1.0293x; 1.0270x over previous
//
#include <hip/hip_runtime.h>
#include <math.h>

// ---------------------------------------------------------------------------
// AsymQuantMatMul: A[4096,2048] fp32, B[2048,4096] fp32 -> out[4096,4096] fp32
// R10: GEMM = exact R4 skeleton (128x128 block, BK=128, 4 waves, 2-barrier,
//      4 blocks/CU, 3-bit XOR swizzle staging verbatim) with the MFMA shape
//      switched 16x16x64 -> 32x32x32 (2x2 frags of 32x32 per wave):
//      +12% i8 shape ceiling, half the MFMA instruction count, identical
//      LDS traffic and 0-conflict read geometry (row-varying chunk-fixed,
//      XOR row&7). C/D layout: col=lane&31, row=(reg&3)+8*(reg>>2)+4*(lane>>5)
//      (HW-verified mapping). Schedule axis frozen after R6/R8/R9 regressions.
// ---------------------------------------------------------------------------

#define M_DIM 4096
#define K_DIM 2048
#define N_DIM 4096

using int4v = __attribute__((ext_vector_type(4))) int;
using int16v = __attribute__((ext_vector_type(16))) int;

typedef __attribute__((address_space(1))) const void glb_cv;
typedef __attribute__((address_space(3))) void lds_v;

__device__ __forceinline__ int qbyte(float x, float rs, float z) {
    // reference: clip(round(x/scale) + zero, 0, 255), shifted by -128
    float q = fminf(fmaxf(rintf(x * rs) + z, 0.0f), 255.0f);
    return (int)q - 128;
}

__device__ __forceinline__ int sum4(int w) {
    return (int)(signed char)(w) + (int)(signed char)(w >> 8) +
           (int)(signed char)(w >> 16) + (int)(signed char)(w >> 24);
}

// ---- Kernel 1: per-block min/max partials (512 A + 512 B); zero colB ----
__global__ void minmax_stage1(const float* __restrict__ A,
                              const float* __restrict__ B,
                              float* __restrict__ partials,
                              int* __restrict__ colB) {
    int b = blockIdx.x;
    if (b < 16) colB[b * 256 + threadIdx.x] = 0;  // init for quant atomics
    const float* src = (b < 512) ? A : B;
    int lb = (b < 512) ? b : b - 512;
    const float4* v = (const float4*)src + (long)lb * 4096;  // 4096 float4/block
    float mn = INFINITY, mx = -INFINITY;
    for (int i = threadIdx.x; i < 4096; i += 256) {
        float4 x = v[i];
        mn = fminf(mn, fminf(fminf(x.x, x.y), fminf(x.z, x.w)));
        mx = fmaxf(mx, fmaxf(fmaxf(x.x, x.y), fmaxf(x.z, x.w)));
    }
    for (int off = 32; off; off >>= 1) {
        mn = fminf(mn, __shfl_down(mn, off));
        mx = fmaxf(mx, __shfl_down(mx, off));
    }
    __shared__ float smn[4], smx[4];
    int w = threadIdx.x >> 6;
    if ((threadIdx.x & 63) == 0) { smn[w] = mn; smx[w] = mx; }
    __syncthreads();
    if (threadIdx.x == 0) {
        mn = fminf(fminf(smn[0], smn[1]), fminf(smn[2], smn[3]));
        mx = fmaxf(fmaxf(smx[0], smx[1]), fmaxf(smx[2], smx[3]));
        partials[2 * b] = mn;
        partials[2 * b + 1] = mx;
    }
}

// ---- Kernel 2: fused quantize. Blocks 0..2047: A (2 rows each, row-major
// i8, + row sums). Blocks 2048..4095: B 64x64 tile transpose (+ col sums).
// Every block deterministically re-reduces all partials -> identical qp.
__global__ void quant_fused(const float* __restrict__ A,
                            const float* __restrict__ B,
                            const float* __restrict__ partials,
                            signed char* __restrict__ A8,
                            signed char* __restrict__ B8T,
                            int* __restrict__ rowA,
                            int* __restrict__ colB,
                            float* __restrict__ qp) {
    int b = blockIdx.x, t = threadIdx.x;

    // -- reduce all 1024 partial pairs (L2/L3-cached after kernel 1) --
    float mnA = INFINITY, mxA = -INFINITY, mnB = INFINITY, mxB = -INFINITY;
    for (int i = t; i < 512; i += 256) {
        mnA = fminf(mnA, partials[2 * i]);
        mxA = fmaxf(mxA, partials[2 * i + 1]);
        mnB = fminf(mnB, partials[2 * (i + 512)]);
        mxB = fmaxf(mxB, partials[2 * (i + 512) + 1]);
    }
    for (int off = 32; off; off >>= 1) {
        mnA = fminf(mnA, __shfl_down(mnA, off));
        mxA = fmaxf(mxA, __shfl_down(mxA, off));
        mnB = fminf(mnB, __shfl_down(mnB, off));
        mxB = fmaxf(mxB, __shfl_down(mxB, off));
    }
    __shared__ float sred[4][4];
    int w = t >> 6;
    if ((t & 63) == 0) { sred[w][0] = mnA; sred[w][1] = mxA; sred[w][2] = mnB; sred[w][3] = mxB; }
    __syncthreads();
    mnA = fminf(fminf(sred[0][0], sred[1][0]), fminf(sred[2][0], sred[3][0]));
    mxA = fmaxf(fmaxf(sred[0][1], sred[1][1]), fmaxf(sred[2][1], sred[3][1]));
    mnB = fminf(fminf(sred[0][2], sred[1][2]), fminf(sred[2][2], sred[3][2]));
    mxB = fmaxf(fmaxf(sred[0][3], sred[1][3]), fmaxf(sred[2][3], sred[3][3]));
    float sA = (mxA - mnA) / 255.0f;
    float zA = rintf(-mnA / sA);
    float sB = (mxB - mnB) / 255.0f;
    float zB = rintf(-mnB / sB);
    if (b == 0 && t == 0) { qp[0] = sA; qp[1] = zA; qp[2] = sB; qp[3] = zB; }
    __syncthreads();

    if (b < 2048) {
        // ---- A path: 2 rows of 2048, fused row sums ----
        float rs = 1.0f / sA, z = zA;
        long base = (long)b * 4096 + (long)t * 16;
        const float4* v = (const float4*)(A + base);
        union { signed char c[16]; int4 i4; } u;
        int ls = 0;
#pragma unroll
        for (int j = 0; j < 4; j++) {
            float4 x = v[j];
            int q0 = qbyte(x.x, rs, z), q1 = qbyte(x.y, rs, z);
            int q2 = qbyte(x.z, rs, z), q3 = qbyte(x.w, rs, z);
            u.c[j * 4 + 0] = (signed char)q0;
            u.c[j * 4 + 1] = (signed char)q1;
            u.c[j * 4 + 2] = (signed char)q2;
            u.c[j * 4 + 3] = (signed char)q3;
            ls += q0 + q1 + q2 + q3;
        }
        *(int4*)(A8 + base) = u.i4;
        for (int off = 32; off; off >>= 1) ls += __shfl_down(ls, off);
        __shared__ int wsum[4];
        if ((t & 63) == 0) wsum[t >> 6] = ls;
        __syncthreads();
        if (t == 0) rowA[b * 2] = wsum[0] + wsum[1];
        if (t == 128) rowA[b * 2 + 1] = wsum[2] + wsum[3];
    } else {
        // ---- B path: 64x64 tile transpose via int-packed LDS, col sums ----
        float rs = 1.0f / sB, z = zB;
        int bb = b - 2048;
        int k0 = (bb & 31) * 64, n0 = (bb >> 5) * 64;
        __shared__ int tile[64][17];  // [n][k/4], +1 pad
        int cn = (t & 15) * 4;  // n offset within tile
        int kg = (t >> 4) * 4;  // k offset within tile
        int w0 = 0, w1 = 0, w2 = 0, w3 = 0;
#pragma unroll
        for (int r = 0; r < 4; r++) {
            float4 x = *(const float4*)&B[(long)(k0 + kg + r) * N_DIM + n0 + cn];
            w0 |= (qbyte(x.x, rs, z) & 255) << (8 * r);
            w1 |= (qbyte(x.y, rs, z) & 255) << (8 * r);
            w2 |= (qbyte(x.z, rs, z) & 255) << (8 * r);
            w3 |= (qbyte(x.w, rs, z) & 255) << (8 * r);
        }
        int kc = kg >> 2;
        tile[cn + 0][kc] = w0;
        tile[cn + 1][kc] = w1;
        tile[cn + 2][kc] = w2;
        tile[cn + 3][kc] = w3;
        __syncthreads();
        int n2 = t >> 2, kb = (t & 3) * 4;
        int4 v;
        v.x = tile[n2][kb + 0];
        v.y = tile[n2][kb + 1];
        v.z = tile[n2][kb + 2];
        v.w = tile[n2][kb + 3];
        *(int4*)&B8T[(long)(n0 + n2) * K_DIM + k0 + (t & 3) * 16] = v;
        int ls = sum4(v.x) + sum4(v.y) + sum4(v.z) + sum4(v.w);
        ls += __shfl_down(ls, 2);
        ls += __shfl_down(ls, 1);
        if ((t & 3) == 0) atomicAdd(&colB[n0 + n2], ls);
    }
}

// ---- Kernel 3: i8 MFMA GEMM (R4 skeleton, 32x32x32 fragments) ----
// 128x128 block, BK=128, 4 waves each 64x64 (2x2 frags of 32x32x32).
// LDS: 16B chunk c of row r stored at slot c ^ (r&7) (3-bit XOR swizzle;
// identical staging + read geometry class to the measured-0-conflict R2).
// Operand map: A row = lane&31, k-chunk = ks*2 + (lane>>5); B symmetric
// (B8T is K-contiguous). Block->tile: 16 regions of 8x8 tiles keyed to XCD.
__global__ __launch_bounds__(256, 4) void gemm_i8(
        const signed char* __restrict__ A8,
        const signed char* __restrict__ B8T,
        const int* __restrict__ rowA,
        const int* __restrict__ colB,
        const float* __restrict__ qp,
        float* __restrict__ out) {
    __shared__ __align__(16) signed char As[128 * 128];  // 16 KB
    __shared__ __align__(16) signed char Bs[128 * 128];  // 16 KB

    // L2-locality block swizzle
    int b = blockIdx.x;
    int xcd = b & 7, i0 = b >> 3;
    int reg = xcd + 8 * (i0 >> 6);    // region 0..15
    int jj0 = i0 & 63;                // 0..63 within region
    int mt = (reg >> 2) * 8 + (jj0 >> 3);
    int nt = (reg & 3) * 8 + (jj0 & 7);
    int r0 = mt * 128, c0 = nt * 128;

    int t = threadIdx.x, lane = t & 63, wave = t >> 6;
    int crow = lane & 31;            // A-row / B-col within 32x32 frag
    int half = lane >> 5;            // k-half selector (16B each)
    int wm = (wave >> 1) * 64;       // wave m offset
    int wn = (wave & 1) * 64;        // wave n offset

    int16v acc[2][2];
#pragma unroll
    for (int i = 0; i < 2; i++)
#pragma unroll
        for (int jj = 0; jj < 2; jj++)
#pragma unroll
            for (int r = 0; r < 16; r++) acc[i][jj][r] = 0;

    // Staging offsets (verbatim R4): LDS chunk ch -> row=ch>>3, slot p=ch&7
    // holds global chunk p ^ (row&7).
    long aoff[4], boff[4];
#pragma unroll
    for (int jj = 0; jj < 4; jj++) {
        int ch = t + 256 * jj;       // 0..1023
        int row = ch >> 3, p = ch & 7;
        int gk = p ^ (row & 7);
        aoff[jj] = (long)(r0 + row) * K_DIM + gk * 16;
        boff[jj] = (long)(c0 + row) * K_DIM + gk * 16;
    }

    int swz = (crow & 7);            // read-side XOR (row&7 == crow&7)

    for (int k0 = 0; k0 < K_DIM; k0 += 128) {
        __syncthreads();  // protect LDS from previous iteration's readers
#pragma unroll
        for (int jj = 0; jj < 4; jj++)
            __builtin_amdgcn_global_load_lds((glb_cv*)(A8 + aoff[jj] + k0),
                                             (lds_v*)(As + (t + 256 * jj) * 16), 16, 0, 0);
#pragma unroll
        for (int jj = 0; jj < 4; jj++)
            __builtin_amdgcn_global_load_lds((glb_cv*)(B8T + boff[jj] + k0),
                                             (lds_v*)(Bs + (t + 256 * jj) * 16), 16, 0, 0);
        __syncthreads();  // staged data visible

#pragma unroll
        for (int ks = 0; ks < 4; ks++) {      // 4 slices of K=32
            int c = ks * 2 + half;            // 16B k-chunk 0..7
            int koff = (c ^ swz) * 16;
            int4v af[2], bf[2];
#pragma unroll
            for (int i = 0; i < 2; i++)
                af[i] = *(const int4v*)&As[(wm + i * 32 + crow) * 128 + koff];
#pragma unroll
            for (int jj = 0; jj < 2; jj++)
                bf[jj] = *(const int4v*)&Bs[(wn + jj * 32 + crow) * 128 + koff];
#pragma unroll
            for (int i = 0; i < 2; i++)
#pragma unroll
                for (int jj = 0; jj < 2; jj++)
                    acc[i][jj] = __builtin_amdgcn_mfma_i32_32x32x32_i8(af[i], bf[jj], acc[i][jj], 0, 0, 0);
        }
    }

    // Epilogue: out = sA*sB*(acc + cB*rowA[m] + cA*colB[n] + K*cA*cB)
    // C/D layout (32x32, HW-verified): col = lane&31,
    // row = (reg&3) + 8*(reg>>2) + 4*(lane>>5), reg = rg*4+rl.
    float sA = qp[0], zA = qp[1], sB = qp[2], zB = qp[3];
    int cA = 128 - (int)zA, cB = 128 - (int)zB;
    float ss = sA * sB;
    int Kzz = K_DIM * cA * cB;
    int ocol0 = c0 + wn + crow;
    int can[2];
#pragma unroll
    for (int jj = 0; jj < 2; jj++) can[jj] = cA * colB[ocol0 + jj * 32];
#pragma unroll
    for (int i = 0; i < 2; i++) {
#pragma unroll
        for (int rg = 0; rg < 4; rg++) {
#pragma unroll
            for (int rl = 0; rl < 4; rl++) {
                int row = r0 + wm + i * 32 + rl + 8 * rg + 4 * half;
                int ra = cB * rowA[row] + Kzz;
                long rbase = (long)row * N_DIM;
#pragma unroll
                for (int jj = 0; jj < 2; jj++) {
                    int v = acc[i][jj][rg * 4 + rl] + ra + can[jj];
                    __builtin_nontemporal_store(ss * (float)v,
                                                &out[rbase + ocol0 + jj * 32]);
                }
            }
        }
    }
}

extern "C" void kernel_launch(void* const* d_in, const int* in_sizes, int n_in,
                              void* d_out, int out_size, void* d_ws, size_t ws_size,
                              hipStream_t stream) {
    const float* A = (const float*)d_in[0];
    const float* B = (const float*)d_in[1];
    float* out = (float*)d_out;
    char* ws = (char*)d_ws;

    signed char* A8  = (signed char*)ws;                    //  8 MB
    signed char* B8T = (signed char*)(ws + 8388608);        //  8 MB
    int*   rowA      = (int*)(ws + 16777216);               // 16 KB
    int*   colB      = (int*)(ws + 16793600);               // 16 KB
    float* partials  = (float*)(ws + 16809984);             //  8 KB
    float* qp        = (float*)(ws + 16818176);             // 16 B

    minmax_stage1<<<1024, 256, 0, stream>>>(A, B, partials, colB);
    quant_fused<<<4096, 256, 0, stream>>>(A, B, partials, A8, B8T, rowA, colB, qp);
    gemm_i8<<<1024, 256, 0, stream>>>(A8, B8T, rowA, colB, qp, out);
}

// Round 7
// 163.532 us; speedup vs baseline: 1.0302x; 1.0009x over previous
//
#include <hip/hip_runtime.h>
#include <math.h>

// ---------------------------------------------------------------------------
// AsymQuantMatMul: A[4096,2048] fp32, B[2048,4096] fp32 -> out[4096,4096] fp32
// R11: R10 (128x128 block, BK=128, 4 waves, 2-barrier, 4 blocks/CU, 32x32x32
//      MFMA) + 4-bit XOR swizzle f(row)=(row&7)^((row>>3)&3). R10's 3-bit
//      swizzle left a 4-way bank conflict (4.2M/dispatch): lanes needing
//      chunk c at rows {r,r+8,r+16,r+24} all hit slot c^(r&7). The extra
//      (row>>3)&3 bits give those 4 rows 4 distinct slots; residual aliasing
//      is 2-way (free, m136). Read-side swz = (crow&7)^(crow>>3) is uniform
//      per lane (wm, i*32 are multiples of 32). Epilogue keeps R10's full
//      128B-line stores (WRITE_SIZE dropped 82->65.5 MB = exact output).
// ---------------------------------------------------------------------------

#define M_DIM 4096
#define K_DIM 2048
#define N_DIM 4096

using int4v = __attribute__((ext_vector_type(4))) int;
using int16v = __attribute__((ext_vector_type(16))) int;

typedef __attribute__((address_space(1))) const void glb_cv;
typedef __attribute__((address_space(3))) void lds_v;

__device__ __forceinline__ int qbyte(float x, float rs, float z) {
    // reference: clip(round(x/scale) + zero, 0, 255), shifted by -128
    float q = fminf(fmaxf(rintf(x * rs) + z, 0.0f), 255.0f);
    return (int)q - 128;
}

__device__ __forceinline__ int sum4(int w) {
    return (int)(signed char)(w) + (int)(signed char)(w >> 8) +
           (int)(signed char)(w >> 16) + (int)(signed char)(w >> 24);
}

// ---- Kernel 1: per-block min/max partials (512 A + 512 B); zero colB ----
__global__ void minmax_stage1(const float* __restrict__ A,
                              const float* __restrict__ B,
                              float* __restrict__ partials,
                              int* __restrict__ colB) {
    int b = blockIdx.x;
    if (b < 16) colB[b * 256 + threadIdx.x] = 0;  // init for quant atomics
    const float* src = (b < 512) ? A : B;
    int lb = (b < 512) ? b : b - 512;
    const float4* v = (const float4*)src + (long)lb * 4096;  // 4096 float4/block
    float mn = INFINITY, mx = -INFINITY;
    for (int i = threadIdx.x; i < 4096; i += 256) {
        float4 x = v[i];
        mn = fminf(mn, fminf(fminf(x.x, x.y), fminf(x.z, x.w)));
        mx = fmaxf(mx, fmaxf(fmaxf(x.x, x.y), fmaxf(x.z, x.w)));
    }
    for (int off = 32; off; off >>= 1) {
        mn = fminf(mn, __shfl_down(mn, off));
        mx = fmaxf(mx, __shfl_down(mx, off));
    }
    __shared__ float smn[4], smx[4];
    int w = threadIdx.x >> 6;
    if ((threadIdx.x & 63) == 0) { smn[w] = mn; smx[w] = mx; }
    __syncthreads();
    if (threadIdx.x == 0) {
        mn = fminf(fminf(smn[0], smn[1]), fminf(smn[2], smn[3]));
        mx = fmaxf(fmaxf(smx[0], smx[1]), fmaxf(smx[2], smx[3]));
        partials[2 * b] = mn;
        partials[2 * b + 1] = mx;
    }
}

// ---- Kernel 2: fused quantize. Blocks 0..2047: A (2 rows each, row-major
// i8, + row sums). Blocks 2048..4095: B 64x64 tile transpose (+ col sums).
// Every block deterministically re-reduces all partials -> identical qp.
__global__ void quant_fused(const float* __restrict__ A,
                            const float* __restrict__ B,
                            const float* __restrict__ partials,
                            signed char* __restrict__ A8,
                            signed char* __restrict__ B8T,
                            int* __restrict__ rowA,
                            int* __restrict__ colB,
                            float* __restrict__ qp) {
    int b = blockIdx.x, t = threadIdx.x;

    // -- reduce all 1024 partial pairs (L2/L3-cached after kernel 1) --
    float mnA = INFINITY, mxA = -INFINITY, mnB = INFINITY, mxB = -INFINITY;
    for (int i = t; i < 512; i += 256) {
        mnA = fminf(mnA, partials[2 * i]);
        mxA = fmaxf(mxA, partials[2 * i + 1]);
        mnB = fminf(mnB, partials[2 * (i + 512)]);
        mxB = fmaxf(mxB, partials[2 * (i + 512) + 1]);
    }
    for (int off = 32; off; off >>= 1) {
        mnA = fminf(mnA, __shfl_down(mnA, off));
        mxA = fmaxf(mxA, __shfl_down(mxA, off));
        mnB = fminf(mnB, __shfl_down(mnB, off));
        mxB = fmaxf(mxB, __shfl_down(mxB, off));
    }
    __shared__ float sred[4][4];
    int w = t >> 6;
    if ((t & 63) == 0) { sred[w][0] = mnA; sred[w][1] = mxA; sred[w][2] = mnB; sred[w][3] = mxB; }
    __syncthreads();
    mnA = fminf(fminf(sred[0][0], sred[1][0]), fminf(sred[2][0], sred[3][0]));
    mxA = fmaxf(fmaxf(sred[0][1], sred[1][1]), fmaxf(sred[2][1], sred[3][1]));
    mnB = fminf(fminf(sred[0][2], sred[1][2]), fminf(sred[2][2], sred[3][2]));
    mxB = fmaxf(fmaxf(sred[0][3], sred[1][3]), fmaxf(sred[2][3], sred[3][3]));
    float sA = (mxA - mnA) / 255.0f;
    float zA = rintf(-mnA / sA);
    float sB = (mxB - mnB) / 255.0f;
    float zB = rintf(-mnB / sB);
    if (b == 0 && t == 0) { qp[0] = sA; qp[1] = zA; qp[2] = sB; qp[3] = zB; }
    __syncthreads();

    if (b < 2048) {
        // ---- A path: 2 rows of 2048, fused row sums ----
        float rs = 1.0f / sA, z = zA;
        long base = (long)b * 4096 + (long)t * 16;
        const float4* v = (const float4*)(A + base);
        union { signed char c[16]; int4 i4; } u;
        int ls = 0;
#pragma unroll
        for (int j = 0; j < 4; j++) {
            float4 x = v[j];
            int q0 = qbyte(x.x, rs, z), q1 = qbyte(x.y, rs, z);
            int q2 = qbyte(x.z, rs, z), q3 = qbyte(x.w, rs, z);
            u.c[j * 4 + 0] = (signed char)q0;
            u.c[j * 4 + 1] = (signed char)q1;
            u.c[j * 4 + 2] = (signed char)q2;
            u.c[j * 4 + 3] = (signed char)q3;
            ls += q0 + q1 + q2 + q3;
        }
        *(int4*)(A8 + base) = u.i4;
        for (int off = 32; off; off >>= 1) ls += __shfl_down(ls, off);
        __shared__ int wsum[4];
        if ((t & 63) == 0) wsum[t >> 6] = ls;
        __syncthreads();
        if (t == 0) rowA[b * 2] = wsum[0] + wsum[1];
        if (t == 128) rowA[b * 2 + 1] = wsum[2] + wsum[3];
    } else {
        // ---- B path: 64x64 tile transpose via int-packed LDS, col sums ----
        float rs = 1.0f / sB, z = zB;
        int bb = b - 2048;
        int k0 = (bb & 31) * 64, n0 = (bb >> 5) * 64;
        __shared__ int tile[64][17];  // [n][k/4], +1 pad
        int cn = (t & 15) * 4;  // n offset within tile
        int kg = (t >> 4) * 4;  // k offset within tile
        int w0 = 0, w1 = 0, w2 = 0, w3 = 0;
#pragma unroll
        for (int r = 0; r < 4; r++) {
            float4 x = *(const float4*)&B[(long)(k0 + kg + r) * N_DIM + n0 + cn];
            w0 |= (qbyte(x.x, rs, z) & 255) << (8 * r);
            w1 |= (qbyte(x.y, rs, z) & 255) << (8 * r);
            w2 |= (qbyte(x.z, rs, z) & 255) << (8 * r);
            w3 |= (qbyte(x.w, rs, z) & 255) << (8 * r);
        }
        int kc = kg >> 2;
        tile[cn + 0][kc] = w0;
        tile[cn + 1][kc] = w1;
        tile[cn + 2][kc] = w2;
        tile[cn + 3][kc] = w3;
        __syncthreads();
        int n2 = t >> 2, kb = (t & 3) * 4;
        int4 v;
        v.x = tile[n2][kb + 0];
        v.y = tile[n2][kb + 1];
        v.z = tile[n2][kb + 2];
        v.w = tile[n2][kb + 3];
        *(int4*)&B8T[(long)(n0 + n2) * K_DIM + k0 + (t & 3) * 16] = v;
        int ls = sum4(v.x) + sum4(v.y) + sum4(v.z) + sum4(v.w);
        ls += __shfl_down(ls, 2);
        ls += __shfl_down(ls, 1);
        if ((t & 3) == 0) atomicAdd(&colB[n0 + n2], ls);
    }
}

// ---- Kernel 3: i8 MFMA GEMM (R4 skeleton, 32x32x32 frags, 4-bit swizzle) --
// 128x128 block, BK=128, 4 waves each 64x64 (2x2 frags of 32x32x32).
// LDS: slot p of row r holds global chunk p ^ f(r), f(r)=(r&7)^((r>>3)&3).
// Cohort {r,r+8,r+16,r+24} needing one chunk -> 4 distinct slots (was the
// 4-way conflict in R10); residual 2-way aliasing is free (m136).
// Operand map: A row = lane&31, k-chunk = ks*2 + (lane>>5); B symmetric.
// Block->tile: 16 regions of 8x8 tiles keyed to XCD.
__global__ __launch_bounds__(256, 4) void gemm_i8(
        const signed char* __restrict__ A8,
        const signed char* __restrict__ B8T,
        const int* __restrict__ rowA,
        const int* __restrict__ colB,
        const float* __restrict__ qp,
        float* __restrict__ out) {
    __shared__ __align__(16) signed char As[128 * 128];  // 16 KB
    __shared__ __align__(16) signed char Bs[128 * 128];  // 16 KB

    // L2-locality block swizzle
    int b = blockIdx.x;
    int xcd = b & 7, i0 = b >> 3;
    int reg = xcd + 8 * (i0 >> 6);    // region 0..15
    int jj0 = i0 & 63;                // 0..63 within region
    int mt = (reg >> 2) * 8 + (jj0 >> 3);
    int nt = (reg & 3) * 8 + (jj0 & 7);
    int r0 = mt * 128, c0 = nt * 128;

    int t = threadIdx.x, lane = t & 63, wave = t >> 6;
    int crow = lane & 31;            // A-row / B-col within 32x32 frag
    int half = lane >> 5;            // k-half selector (16B each)
    int wm = (wave >> 1) * 64;       // wave m offset
    int wn = (wave & 1) * 64;        // wave n offset

    int16v acc[2][2];
#pragma unroll
    for (int i = 0; i < 2; i++)
#pragma unroll
        for (int jj = 0; jj < 2; jj++)
#pragma unroll
            for (int r = 0; r < 16; r++) acc[i][jj][r] = 0;

    // Staging offsets: LDS chunk ch -> row=ch>>3, slot p=ch&7 holds global
    // chunk p ^ f(row), f(row) = (row&7) ^ ((row>>3)&3).
    long aoff[4], boff[4];
#pragma unroll
    for (int jj = 0; jj < 4; jj++) {
        int ch = t + 256 * jj;       // 0..1023
        int row = ch >> 3, p = ch & 7;
        int gk = p ^ (row & 7) ^ ((row >> 3) & 3);
        aoff[jj] = (long)(r0 + row) * K_DIM + gk * 16;
        boff[jj] = (long)(c0 + row) * K_DIM + gk * 16;
    }

    // Read-side XOR: f(row) for row = wm + i*32 + crow reduces to
    // (crow&7) ^ (crow>>3) since wm + i*32 is a multiple of 32.
    int swz = (crow & 7) ^ (crow >> 3);

    for (int k0 = 0; k0 < K_DIM; k0 += 128) {
        __syncthreads();  // protect LDS from previous iteration's readers
#pragma unroll
        for (int jj = 0; jj < 4; jj++)
            __builtin_amdgcn_global_load_lds((glb_cv*)(A8 + aoff[jj] + k0),
                                             (lds_v*)(As + (t + 256 * jj) * 16), 16, 0, 0);
#pragma unroll
        for (int jj = 0; jj < 4; jj++)
            __builtin_amdgcn_global_load_lds((glb_cv*)(B8T + boff[jj] + k0),
                                             (lds_v*)(Bs + (t + 256 * jj) * 16), 16, 0, 0);
        __syncthreads();  // staged data visible

#pragma unroll
        for (int ks = 0; ks < 4; ks++) {      // 4 slices of K=32
            int c = ks * 2 + half;            // 16B k-chunk 0..7
            int koff = (c ^ swz) * 16;
            int4v af[2], bf[2];
#pragma unroll
            for (int i = 0; i < 2; i++)
                af[i] = *(const int4v*)&As[(wm + i * 32 + crow) * 128 + koff];
#pragma unroll
            for (int jj = 0; jj < 2; jj++)
                bf[jj] = *(const int4v*)&Bs[(wn + jj * 32 + crow) * 128 + koff];
#pragma unroll
            for (int i = 0; i < 2; i++)
#pragma unroll
                for (int jj = 0; jj < 2; jj++)
                    acc[i][jj] = __builtin_amdgcn_mfma_i32_32x32x32_i8(af[i], bf[jj], acc[i][jj], 0, 0, 0);
        }
    }

    // Epilogue: out = sA*sB*(acc + cB*rowA[m] + cA*colB[n] + K*cA*cB)
    // C/D layout (32x32, HW-verified): col = lane&31,
    // row = (reg&3) + 8*(reg>>2) + 4*(lane>>5), reg = rg*4+rl.
    float sA = qp[0], zA = qp[1], sB = qp[2], zB = qp[3];
    int cA = 128 - (int)zA, cB = 128 - (int)zB;
    float ss = sA * sB;
    int Kzz = K_DIM * cA * cB;
    int ocol0 = c0 + wn + crow;
    int can[2];
#pragma unroll
    for (int jj = 0; jj < 2; jj++) can[jj] = cA * colB[ocol0 + jj * 32];
#pragma unroll
    for (int i = 0; i < 2; i++) {
#pragma unroll
        for (int rg = 0; rg < 4; rg++) {
#pragma unroll
            for (int rl = 0; rl < 4; rl++) {
                int row = r0 + wm + i * 32 + rl + 8 * rg + 4 * half;
                int ra = cB * rowA[row] + Kzz;
                long rbase = (long)row * N_DIM;
#pragma unroll
                for (int jj = 0; jj < 2; jj++) {
                    int v = acc[i][jj][rg * 4 + rl] + ra + can[jj];
                    __builtin_nontemporal_store(ss * (float)v,
                                                &out[rbase + ocol0 + jj * 32]);
                }
            }
        }
    }
}

extern "C" void kernel_launch(void* const* d_in, const int* in_sizes, int n_in,
                              void* d_out, int out_size, void* d_ws, size_t ws_size,
                              hipStream_t stream) {
    const float* A = (const float*)d_in[0];
    const float* B = (const float*)d_in[1];
    float* out = (float*)d_out;
    char* ws = (char*)d_ws;

    signed char* A8  = (signed char*)ws;                    //  8 MB
    signed char* B8T = (signed char*)(ws + 8388608);        //  8 MB
    int*   rowA      = (int*)(ws + 16777216);               // 16 KB
    int*   colB      = (int*)(ws + 16793600);               // 16 KB
    float* partials  = (float*)(ws + 16809984);             //  8 KB
    float* qp        = (float*)(ws + 16818176);             // 16 B

    minmax_stage1<<<1024, 256, 0, stream>>>(A, B, partials, colB);
    quant_fused<<<4096, 256, 0, stream>>>(A, B, partials, A8, B8T, rowA, colB, qp);
    gemm_i8<<<1024, 256, 0, stream>>>(A8, B8T, rowA, colB, qp, out);
}

// Round 8
// 159.102 us; speedup vs baseline: 1.0588x; 1.0278x over previous
//
#include <hip/hip_runtime.h>
#include <math.h>

// ---------------------------------------------------------------------------
// AsymQuantMatMul: A[4096,2048] fp32, B[2048,4096] fp32 -> out[4096,4096] fp32
// R12: consolidation = exact R0/R4 configuration (best measured: total 161.2,
//      gemm 44.5). GEMM: mfma_i32_16x16x64_i8, 128x128 block, BK=128,
//      3-bit XOR swizzle (measured 0 conflicts), XCD L2 regioning,
//      __launch_bounds__(256,4), nontemporal stores.
//      Session ledger: schedule variants (dbuf drain-0 49.6, coarse counted
//      56.6, fine counted 53-57), tiles (256x128 46.7), shapes (32x32x32
//      45.2), 4-bit 0-conflict swizzle (48.2), full-line epilogue (no dur
//      change) -- all neutral or negative vs this structure. Binding term is
//      the per-K-step global_load_lds drain at the barrier, already best
//      hidden by 4 blocks/CU cross-block TLP.
// ---------------------------------------------------------------------------

#define M_DIM 4096
#define K_DIM 2048
#define N_DIM 4096

using int4v = __attribute__((ext_vector_type(4))) int;

typedef __attribute__((address_space(1))) const void glb_cv;
typedef __attribute__((address_space(3))) void lds_v;

__device__ __forceinline__ int qbyte(float x, float rs, float z) {
    // reference: clip(round(x/scale) + zero, 0, 255), shifted by -128
    float q = fminf(fmaxf(rintf(x * rs) + z, 0.0f), 255.0f);
    return (int)q - 128;
}

__device__ __forceinline__ int sum4(int w) {
    return (int)(signed char)(w) + (int)(signed char)(w >> 8) +
           (int)(signed char)(w >> 16) + (int)(signed char)(w >> 24);
}

// ---- Kernel 1: per-block min/max partials (512 A + 512 B); zero colB ----
__global__ void minmax_stage1(const float* __restrict__ A,
                              const float* __restrict__ B,
                              float* __restrict__ partials,
                              int* __restrict__ colB) {
    int b = blockIdx.x;
    if (b < 16) colB[b * 256 + threadIdx.x] = 0;  // init for quant atomics
    const float* src = (b < 512) ? A : B;
    int lb = (b < 512) ? b : b - 512;
    const float4* v = (const float4*)src + (long)lb * 4096;  // 4096 float4/block
    float mn = INFINITY, mx = -INFINITY;
    for (int i = threadIdx.x; i < 4096; i += 256) {
        float4 x = v[i];
        mn = fminf(mn, fminf(fminf(x.x, x.y), fminf(x.z, x.w)));
        mx = fmaxf(mx, fmaxf(fmaxf(x.x, x.y), fmaxf(x.z, x.w)));
    }
    for (int off = 32; off; off >>= 1) {
        mn = fminf(mn, __shfl_down(mn, off));
        mx = fmaxf(mx, __shfl_down(mx, off));
    }
    __shared__ float smn[4], smx[4];
    int w = threadIdx.x >> 6;
    if ((threadIdx.x & 63) == 0) { smn[w] = mn; smx[w] = mx; }
    __syncthreads();
    if (threadIdx.x == 0) {
        mn = fminf(fminf(smn[0], smn[1]), fminf(smn[2], smn[3]));
        mx = fmaxf(fmaxf(smx[0], smx[1]), fmaxf(smx[2], smx[3]));
        partials[2 * b] = mn;
        partials[2 * b + 1] = mx;
    }
}

// ---- Kernel 2: fused quantize. Blocks 0..2047: A (2 rows each, row-major
// i8, + row sums). Blocks 2048..4095: B 64x64 tile transpose (+ col sums).
// Every block deterministically re-reduces all partials -> identical qp.
__global__ void quant_fused(const float* __restrict__ A,
                            const float* __restrict__ B,
                            const float* __restrict__ partials,
                            signed char* __restrict__ A8,
                            signed char* __restrict__ B8T,
                            int* __restrict__ rowA,
                            int* __restrict__ colB,
                            float* __restrict__ qp) {
    int b = blockIdx.x, t = threadIdx.x;

    // -- reduce all 1024 partial pairs (L2/L3-cached after kernel 1) --
    float mnA = INFINITY, mxA = -INFINITY, mnB = INFINITY, mxB = -INFINITY;
    for (int i = t; i < 512; i += 256) {
        mnA = fminf(mnA, partials[2 * i]);
        mxA = fmaxf(mxA, partials[2 * i + 1]);
        mnB = fminf(mnB, partials[2 * (i + 512)]);
        mxB = fmaxf(mxB, partials[2 * (i + 512) + 1]);
    }
    for (int off = 32; off; off >>= 1) {
        mnA = fminf(mnA, __shfl_down(mnA, off));
        mxA = fmaxf(mxA, __shfl_down(mxA, off));
        mnB = fminf(mnB, __shfl_down(mnB, off));
        mxB = fmaxf(mxB, __shfl_down(mxB, off));
    }
    __shared__ float sred[4][4];
    int w = t >> 6;
    if ((t & 63) == 0) { sred[w][0] = mnA; sred[w][1] = mxA; sred[w][2] = mnB; sred[w][3] = mxB; }
    __syncthreads();
    mnA = fminf(fminf(sred[0][0], sred[1][0]), fminf(sred[2][0], sred[3][0]));
    mxA = fmaxf(fmaxf(sred[0][1], sred[1][1]), fmaxf(sred[2][1], sred[3][1]));
    mnB = fminf(fminf(sred[0][2], sred[1][2]), fminf(sred[2][2], sred[3][2]));
    mxB = fmaxf(fmaxf(sred[0][3], sred[1][3]), fmaxf(sred[2][3], sred[3][3]));
    float sA = (mxA - mnA) / 255.0f;
    float zA = rintf(-mnA / sA);
    float sB = (mxB - mnB) / 255.0f;
    float zB = rintf(-mnB / sB);
    if (b == 0 && t == 0) { qp[0] = sA; qp[1] = zA; qp[2] = sB; qp[3] = zB; }
    __syncthreads();

    if (b < 2048) {
        // ---- A path: 2 rows of 2048, fused row sums ----
        float rs = 1.0f / sA, z = zA;
        long base = (long)b * 4096 + (long)t * 16;
        const float4* v = (const float4*)(A + base);
        union { signed char c[16]; int4 i4; } u;
        int ls = 0;
#pragma unroll
        for (int j = 0; j < 4; j++) {
            float4 x = v[j];
            int q0 = qbyte(x.x, rs, z), q1 = qbyte(x.y, rs, z);
            int q2 = qbyte(x.z, rs, z), q3 = qbyte(x.w, rs, z);
            u.c[j * 4 + 0] = (signed char)q0;
            u.c[j * 4 + 1] = (signed char)q1;
            u.c[j * 4 + 2] = (signed char)q2;
            u.c[j * 4 + 3] = (signed char)q3;
            ls += q0 + q1 + q2 + q3;
        }
        *(int4*)(A8 + base) = u.i4;
        for (int off = 32; off; off >>= 1) ls += __shfl_down(ls, off);
        __shared__ int wsum[4];
        if ((t & 63) == 0) wsum[t >> 6] = ls;
        __syncthreads();
        if (t == 0) rowA[b * 2] = wsum[0] + wsum[1];
        if (t == 128) rowA[b * 2 + 1] = wsum[2] + wsum[3];
    } else {
        // ---- B path: 64x64 tile transpose via int-packed LDS, col sums ----
        float rs = 1.0f / sB, z = zB;
        int bb = b - 2048;
        int k0 = (bb & 31) * 64, n0 = (bb >> 5) * 64;
        __shared__ int tile[64][17];  // [n][k/4], +1 pad
        int cn = (t & 15) * 4;  // n offset within tile
        int kg = (t >> 4) * 4;  // k offset within tile
        int w0 = 0, w1 = 0, w2 = 0, w3 = 0;
#pragma unroll
        for (int r = 0; r < 4; r++) {
            float4 x = *(const float4*)&B[(long)(k0 + kg + r) * N_DIM + n0 + cn];
            w0 |= (qbyte(x.x, rs, z) & 255) << (8 * r);
            w1 |= (qbyte(x.y, rs, z) & 255) << (8 * r);
            w2 |= (qbyte(x.z, rs, z) & 255) << (8 * r);
            w3 |= (qbyte(x.w, rs, z) & 255) << (8 * r);
        }
        int kc = kg >> 2;
        tile[cn + 0][kc] = w0;
        tile[cn + 1][kc] = w1;
        tile[cn + 2][kc] = w2;
        tile[cn + 3][kc] = w3;
        __syncthreads();
        int n2 = t >> 2, kb = (t & 3) * 4;
        int4 v;
        v.x = tile[n2][kb + 0];
        v.y = tile[n2][kb + 1];
        v.z = tile[n2][kb + 2];
        v.w = tile[n2][kb + 3];
        *(int4*)&B8T[(long)(n0 + n2) * K_DIM + k0 + (t & 3) * 16] = v;
        int ls = sum4(v.x) + sum4(v.y) + sum4(v.z) + sum4(v.w);
        ls += __shfl_down(ls, 2);
        ls += __shfl_down(ls, 1);
        if ((t & 3) == 0) atomicAdd(&colB[n0 + n2], ls);
    }
}

// ---- Kernel 3: i8 MFMA GEMM (R2 structure, 4 blocks/CU) ----
// 128x128 block, BK=128, 4 waves each 64x64 (4x4 frags of 16x16x64).
// LDS: 16B chunk c of row r stored at slot c ^ (r&7) (3-bit XOR swizzle;
// this exact read geometry measured 0 bank conflicts).
// Block->tile: 16 regions of 8x8 tiles keyed to XCD for L2 locality.
__global__ __launch_bounds__(256, 4) void gemm_i8(
        const signed char* __restrict__ A8,
        const signed char* __restrict__ B8T,
        const int* __restrict__ rowA,
        const int* __restrict__ colB,
        const float* __restrict__ qp,
        float* __restrict__ out) {
    __shared__ __align__(16) signed char As[128 * 128];  // 16 KB
    __shared__ __align__(16) signed char Bs[128 * 128];  // 16 KB

    // L2-locality block swizzle
    int b = blockIdx.x;
    int xcd = b & 7, i0 = b >> 3;
    int reg = xcd + 8 * (i0 >> 6);    // region 0..15
    int jj0 = i0 & 63;                // 0..63 within region
    int mt = (reg >> 2) * 8 + (jj0 >> 3);
    int nt = (reg & 3) * 8 + (jj0 & 7);
    int r0 = mt * 128, c0 = nt * 128;

    int t = threadIdx.x, lane = t & 63, wave = t >> 6;
    int mrow = lane & 15;
    int g = lane >> 4;               // k-group 0..3
    int wm = (wave >> 1) * 64;       // wave m offset
    int wn = (wave & 1) * 64;        // wave n offset

    int4v acc[4][4];
#pragma unroll
    for (int i = 0; i < 4; i++)
#pragma unroll
        for (int jj = 0; jj < 4; jj++) acc[i][jj] = (int4v){0, 0, 0, 0};

    // Staging offsets: LDS chunk ch -> row=ch>>3, slot p=ch&7 holds global
    // chunk p ^ (row&7).
    long aoff[4], boff[4];
#pragma unroll
    for (int jj = 0; jj < 4; jj++) {
        int ch = t + 256 * jj;       // 0..1023
        int row = ch >> 3, p = ch & 7;
        int gk = p ^ (row & 7);
        aoff[jj] = (long)(r0 + row) * K_DIM + gk * 16;
        boff[jj] = (long)(c0 + row) * K_DIM + gk * 16;
    }

    int swz = (mrow & 7);            // read-side XOR

    for (int k0 = 0; k0 < K_DIM; k0 += 128) {
        __syncthreads();  // protect LDS from previous iteration's readers
#pragma unroll
        for (int jj = 0; jj < 4; jj++)
            __builtin_amdgcn_global_load_lds((glb_cv*)(A8 + aoff[jj] + k0),
                                             (lds_v*)(As + (t + 256 * jj) * 16), 16, 0, 0);
#pragma unroll
        for (int jj = 0; jj < 4; jj++)
            __builtin_amdgcn_global_load_lds((glb_cv*)(B8T + boff[jj] + k0),
                                             (lds_v*)(Bs + (t + 256 * jj) * 16), 16, 0, 0);
        __syncthreads();  // staged data visible

#pragma unroll
        for (int ks = 0; ks < 2; ks++) {
            int c = ks * 4 + g;
            int koff = (c ^ swz) * 16;
            int4v af[4], bf[4];
#pragma unroll
            for (int i = 0; i < 4; i++)
                af[i] = *(const int4v*)&As[(wm + i * 16 + mrow) * 128 + koff];
#pragma unroll
            for (int jj = 0; jj < 4; jj++)
                bf[jj] = *(const int4v*)&Bs[(wn + jj * 16 + mrow) * 128 + koff];
#pragma unroll
            for (int i = 0; i < 4; i++)
#pragma unroll
                for (int jj = 0; jj < 4; jj++)
                    acc[i][jj] = __builtin_amdgcn_mfma_i32_16x16x64_i8(af[i], bf[jj], acc[i][jj], 0, 0, 0);
        }
    }

    // Epilogue: out = sA*sB*(acc + cB*rowA[m] + cA*colB[n] + K*cA*cB)
    float sA = qp[0], zA = qp[1], sB = qp[2], zB = qp[3];
    int cA = 128 - (int)zA, cB = 128 - (int)zB;
    float ss = sA * sB;
    int Kzz = K_DIM * cA * cB;
    int ocol = c0 + wn + mrow;
    int orow = r0 + wm + g * 4;
#pragma unroll
    for (int i = 0; i < 4; i++) {
        int ra[4];
#pragma unroll
        for (int rr = 0; rr < 4; rr++) ra[rr] = cB * rowA[orow + i * 16 + rr] + Kzz;
#pragma unroll
        for (int jj = 0; jj < 4; jj++) {
            int cc = ocol + jj * 16;
            int can = cA * colB[cc];
#pragma unroll
            for (int rr = 0; rr < 4; rr++) {
                int v = acc[i][jj][rr] + ra[rr] + can;
                __builtin_nontemporal_store(ss * (float)v,
                                            &out[(long)(orow + i * 16 + rr) * N_DIM + cc]);
            }
        }
    }
}

extern "C" void kernel_launch(void* const* d_in, const int* in_sizes, int n_in,
                              void* d_out, int out_size, void* d_ws, size_t ws_size,
                              hipStream_t stream) {
    const float* A = (const float*)d_in[0];
    const float* B = (const float*)d_in[1];
    float* out = (float*)d_out;
    char* ws = (char*)d_ws;

    signed char* A8  = (signed char*)ws;                    //  8 MB
    signed char* B8T = (signed char*)(ws + 8388608);        //  8 MB
    int*   rowA      = (int*)(ws + 16777216);               // 16 KB
    int*   colB      = (int*)(ws + 16793600);               // 16 KB
    float* partials  = (float*)(ws + 16809984);             //  8 KB
    float* qp        = (float*)(ws + 16818176);             // 16 B

    minmax_stage1<<<1024, 256, 0, stream>>>(A, B, partials, colB);
    quant_fused<<<4096, 256, 0, stream>>>(A, B, partials, A8, B8T, rowA, colB, qp);
    gemm_i8<<<1024, 256, 0, stream>>>(A8, B8T, rowA, colB, qp, out);
}